// Round 4
// baseline (141.321 us; speedup 1.0000x reference)
//
#pragma clang fp contract(off)
#include <hip/hip_runtime.h>
#include <hip/hip_bf16.h>

typedef unsigned long long u64;
typedef unsigned int u32;

#define NPTS   200000
#define MBOX   128
#define W64    3125      // NPTS / 64 exactly
#define W64C   3200      // padded word count (25 chunks * 128)
#define NCH    25
#define CW     128       // words per kB chunk
#define ITILE  8         // i-rows per kB block
#define SSAMP  256
#define AANCH  3
#define VOXELF 0.4f
#define PCSF   -75.2f

// ---------------- Kernel A: per-point 128-bit box masks -> col-major + row-major bitmaps ----
// colbits[w*128 + m] : coalesced for kB's j-dimension
// rowbits[m*W64C + w]: coalesced for kD's per-row scans
__global__ __launch_bounds__(256) void kA(const float* __restrict__ points,
                                          const float* __restrict__ boxes,
                                          u64* __restrict__ colbits,
                                          u64* __restrict__ rowbits,
                                          u32* __restrict__ inter)
{
    __shared__ float sbx[128], sby[128], sr[128], sqx[128], sqy[128], srv[128];
    int tid = threadIdx.x;
    // fold inter zero-init into this kernel (runs before kB in stream order)
    if (blockIdx.x < 64) inter[blockIdx.x * 256 + tid] = 0;
    if (tid < 128) {
        float bx = boxes[tid*7+0], by = boxes[tid*7+1];
        float dx = boxes[tid*7+3], dy = boxes[tid*7+4];
        float hx = dx * 0.5f, hy = dy * 0.5f;
        float sq = hx*hx;
        sq = sq + hy*hy;
        float r = sqrtf(sq);                     // radii (GAMMA=1)
        sbx[tid] = bx; sby[tid] = by; sr[tid] = r;
        sqx[tid] = floorf((bx - PCSF) / VOXELF);
        sqy[tid] = floorf((by - PCSF) / VOXELF);
        srv[tid] = ceilf(r / VOXELF);            // rad_vox
    }
    __syncthreads();
    int w = blockIdx.x * 4 + (tid >> 6);         // w in [0, W64C)
    int lane = tid & 63;
    int n = w * 64 + lane;
    bool valid = (n < NPTS);
    float px = 1e9f, py = 1e9f;
    if (valid) { px = points[n*5+0]; py = points[n*5+1]; }
    float cxn = floorf((px - PCSF) / VOXELF);
    float cyn = floorf((py - PCSF) / VOXELF);
    u64 lo = 0, hi = 0;
    bool voxany = false;
    for (int m = 0; m < 128; ++m) {
        float ddx = px - sbx[m], ddy = py - sby[m];
        float sq = ddx*ddx;
        sq = sq + ddy*ddy;
        float dis = sqrtf(sq);
        bool hit = (dis <= sr[m]);
        float aqx = fabsf(sqx[m] - cxn), aqy = fabsf(sqy[m] - cyn);
        bool vox = (aqx < srv[m]) & (aqy < srv[m]);
        voxany |= vox;
        if (m < 64) lo |= ((u64)hit) << m;
        else        hi |= ((u64)hit) << (m - 64);
    }
    if (!voxany) { lo = 0; hi = 0; }   // point_mask = circle & vmask
    u64 mylo = 0, myhi = 0;
    for (int m = 0; m < 64; ++m) {
        u64 bal = __ballot(((lo >> m) & 1ull) != 0);
        if (lane == m) mylo = bal;
    }
    for (int m = 0; m < 64; ++m) {
        u64 bal = __ballot(((hi >> m) & 1ull) != 0);
        if (lane == m) myhi = bal;
    }
    colbits[(size_t)w * 128 + lane]      = mylo;   // coalesced 512B per wave
    colbits[(size_t)w * 128 + 64 + lane] = myhi;
    rowbits[(size_t)lane * W64C + w]        = mylo; // scatter, 8B per lane
    rowbits[(size_t)(lane + 64) * W64C + w] = myhi;
}

// ---------------- Kernel B: inter[i][j] += popcount(row_i & row_j), tiled bit-GEMM ----------------
__global__ __launch_bounds__(256) void kB(const u64* __restrict__ colbits,
                                          u32* __restrict__ inter)
{
    __shared__ u64 ldsI[CW * ITILE];   // [k][i] : 8KB
    __shared__ u32 part[128 * ITILE];  // 4KB
    int blk = blockIdx.x;
    int itile = blk / NCH, ch = blk % NCH;
    int i0 = itile * ITILE, w0 = ch * CW;
    int tid = threadIdx.x;
    for (int idx = tid; idx < CW * ITILE; idx += 256) {
        int w = idx >> 3, i = idx & 7;
        ldsI[idx] = colbits[(size_t)(w0 + w) * 128 + i0 + i];
    }
    __syncthreads();
    int j = tid & 127, dup = tid >> 7;     // dup splits the w-chunk in half
    u32 acc[ITILE] = {0,0,0,0,0,0,0,0};
    int kbeg = dup * (CW/2), kend = kbeg + (CW/2);
    #pragma unroll 2
    for (int k = kbeg; k < kend; ++k) {
        u64 rj = colbits[(size_t)(w0 + k) * 128 + j];   // coalesced across lanes
        #pragma unroll
        for (int i = 0; i < ITILE; ++i)
            acc[i] += (u32)__popcll(rj & ldsI[k * ITILE + i]);
    }
    if (dup == 1) {
        #pragma unroll
        for (int i = 0; i < ITILE; ++i) part[j * ITILE + i] = acc[i];
    }
    __syncthreads();
    if (dup == 0) {
        #pragma unroll
        for (int i = 0; i < ITILE; ++i)
            atomicAdd(&inter[(i0 + i) * 128 + j], acc[i] + part[j * ITILE + i]);
    }
}

// ---------------- Kernel C: miou argmax (LDS) + greedy grouping (register wave scan) --------
// NOTE: must be launched with 256 threads (loop strides assume it).
__global__ __launch_bounds__(256) void kC(const u32* __restrict__ inter,
                                          const int* __restrict__ labels,
                                          const int* __restrict__ pNA,
                                          int* __restrict__ aidx_ws,
                                          float* __restrict__ out_anchor)
{
    __shared__ u32 sInt[128 * 128];    // 64KB
    __shared__ int sLab[128];
    __shared__ float sMax[128];
    __shared__ int sIdx[128];
    __shared__ int sA[128 * AANCH];
    int tid = threadIdx.x;
    const uint4* ip = (const uint4*)inter;
    uint4* sp = (uint4*)sInt;
    for (int t = tid; t < 4096; t += 256) sp[t] = ip[t];   // coalesced 64KB
    if (tid < 128) sLab[tid] = labels[tid];
    __syncthreads();
    if (tid < 128) {
        u32 ci = sInt[tid * 128 + tid];
        int li = sLab[tid];
        float best = 0.0f; int bidx = 0;
        for (int j = 0; j < 128; ++j) {
            if (j == tid) continue;
            if (sLab[j] != li) continue;
            u32 I = sInt[tid * 128 + j];
            u32 cj = sInt[j * 128 + j];
            long un = (long)ci + (long)cj - (long)I;
            if (un > 0) {
                float v = (float)I / fmaxf((float)un, 1.0f);
                if (v > best) { best = v; bidx = j; }   // strict > : first-index argmax
            }
        }
        sMax[tid] = best; sIdx[tid] = bidx;
    }
    __syncthreads();
    // ---- serial greedy scan on wave 0; all state register-resident ----
    if (tid < 64) {
        int NA = *pNA;
        int   mia = sIdx[tid], mib = sIdx[tid + 64];
        int   mxa = __float_as_int(sMax[tid]), mxb = __float_as_int(sMax[tid + 64]);
        int gofa = -1, gofb = -1;
        int gca = 0, gcb = 0;
        int aL0 = -1, aL1 = -1, aL2 = -1, aH0 = -1, aH1 = -1, aH2 = -1;
        int ng = 0;
        for (int i = 0; i < 128; ++i) {
            int j = (i < 64) ? __builtin_amdgcn_readlane(mia, i)
                             : __builtin_amdgcn_readlane(mib, i - 64);
            float mx = __int_as_float((i < 64) ? __builtin_amdgcn_readlane(mxa, i)
                                               : __builtin_amdgcn_readlane(mxb, i - 64));
            int gj = (j < 64) ? __builtin_amdgcn_readlane(gofa, j)
                              : __builtin_amdgcn_readlane(gofb, j - 64);
            int gjs = gj > 0 ? gj : 0;
            int gc = (gjs < 64) ? __builtin_amdgcn_readlane(gca, gjs)
                                : __builtin_amdgcn_readlane(gcb, gjs - 64);
            bool join = (mx > 0.5f) && (gj >= 0) && (gc < NA);
            int tg = join ? gjs : ng;
            int ts = join ? gc : 0;
            bool ownL = (tid == (tg & 63)) && (tg < 64);
            bool ownH = (tid == (tg & 63)) && (tg >= 64);
            if (ts == 0)      { if (ownL) aL0 = i; if (ownH) aH0 = i; }
            else if (ts == 1) { if (ownL) aL1 = i; if (ownH) aH1 = i; }
            else              { if (ownL) aL2 = i; if (ownH) aH2 = i; }
            if (tid == (i & 63)) { if (i < 64) gofa = tg; else gofb = tg; }
            if (ownL) gca += 1;
            if (ownH) gcb += 1;
            ng += join ? 0 : 1;
        }
        sA[tid * 3 + 0] = aL0; sA[tid * 3 + 1] = aL1; sA[tid * 3 + 2] = aL2;
        sA[(tid + 64) * 3 + 0] = aH0; sA[(tid + 64) * 3 + 1] = aH1; sA[(tid + 64) * 3 + 2] = aH2;
    }
    __syncthreads();
    for (int t = tid; t < 128 * AANCH; t += 256) {
        int v = sA[t];
        aidx_ws[t] = v;
        out_anchor[t] = (float)v;      // int32 ref chunk read back as f32 values
    }
}

// ---------------- Kernel D: merged masks, ordered top-k selection, gather ----------------
__global__ __launch_bounds__(256) void kD(const u64* __restrict__ rowbits,
                                          const int* __restrict__ aidx_ws,
                                          const float* __restrict__ points,
                                          float* __restrict__ out)
{
    int g = blockIdx.x, tid = threadIdx.x;
    __shared__ u32 sl3[256], sl2[256], sl1[256];
    __shared__ u64 wtot[4];
    __shared__ u64 carried;
    float* outg = out + (size_t)g * SSAMP * 5;
    int a0 = aidx_ws[g*3+0], a1 = aidx_ws[g*3+1], a2 = aidx_ws[g*3+2];
    if (a0 < 0) {                      // invalid group -> all zeros
        for (int t = tid; t < SSAMP * 5; t += 256) outg[t] = 0.0f;
        return;
    }
    bool vB = (a1 >= 0), vC = (a2 >= 0);
    const u64* rA = rowbits + (size_t)a0 * W64C;
    const u64* rB = rowbits + (size_t)(vB ? a1 : 0) * W64C;
    const u64* rC = rowbits + (size_t)(vC ? a2 : 0) * W64C;
    if (tid == 0) carried = 0;
    __syncthreads();
    int lane = tid & 63, wv = tid >> 6;
    const u64 M21 = (1ull << 21) - 1;
    for (int ch = 0; ch < 13; ++ch) {
        int w = ch * 256 + tid;
        bool inr = (w < W64);
        u64 a = 0, b = 0, c = 0;
        if (inr) {
            a = rA[w];                          // coalesced
            b = vB ? rB[w] : 0ull;
            c = vC ? rC[w] : 0ull;
        }
        u64 m3 = a & b & c;
        u64 any2 = (a & b) | (a & c) | (b & c);
        u64 m2 = any2 & ~m3;
        u64 m1 = (a | b | c) & ~any2;
        u64 p = ((u64)__popcll(m3) << 42) | ((u64)__popcll(m2) << 21) | (u64)__popcll(m1);
        u64 own = p;
        for (int d = 1; d < 64; d <<= 1) {       // inclusive wave scan (packed fields)
            u64 t = __shfl_up(p, d);
            if (lane >= d) p += t;
        }
        if (lane == 63) wtot[wv] = p;
        u64 excl = p - own;
        __syncthreads();
        u64 off = carried + excl;
        for (int k = 0; k < wv; ++k) off += wtot[k];
        u32 e3 = (u32)(off >> 42);
        u32 e2 = (u32)((off >> 21) & M21);
        u32 e1 = (u32)(off & M21);
        int nb = w * 64;
        u64 mm = m3; u32 o = e3;
        while (mm) { int b2 = __builtin_ctzll(mm); mm &= mm - 1; if (o < 256) sl3[o] = nb + b2; o++; }
        mm = m2; o = e2;
        while (mm) { int b2 = __builtin_ctzll(mm); mm &= mm - 1; if (o < 256) sl2[o] = nb + b2; o++; }
        mm = m1; o = e1;
        while (mm) { int b2 = __builtin_ctzll(mm); mm &= mm - 1; if (o < 256) sl1[o] = nb + b2; o++; }
        __syncthreads();
        if (tid == 0) carried += wtot[0] + wtot[1] + wtot[2] + wtot[3];
        __syncthreads();
    }
    u64 car = carried;
    u32 t3 = (u32)(car >> 42), t2 = (u32)((car >> 21) & M21), t1 = (u32)(car & M21);
    u32 s = (u32)tid;
    int n = -1;
    if (s < t3)                 n = (int)sl3[s];
    else if (s < t3 + t2)       n = (int)sl2[s - t3];
    else if (s < t3 + t2 + t1)  n = (int)sl1[s - t3 - t2];
    float v0=0.f, v1=0.f, v2=0.f, v3=0.f, v4=0.f;
    if (n >= 0) {
        const float* pp = points + (size_t)n * 5;
        v0 = pp[0]; v1 = pp[1]; v2 = pp[2]; v3 = pp[3]; v4 = pp[4];
    }
    outg[s*5+0] = v0; outg[s*5+1] = v1; outg[s*5+2] = v2;
    outg[s*5+3] = v3; outg[s*5+4] = v4;
}

extern "C" void kernel_launch(void* const* d_in, const int* in_sizes, int n_in,
                              void* d_out, int out_size, void* d_ws, size_t ws_size,
                              hipStream_t stream)
{
    const float* points = (const float*)d_in[0];
    const float* boxes  = (const float*)d_in[1];
    const int*   labels = (const int*)d_in[2];
    const int*   pNA    = (const int*)d_in[4];
    float* out = (float*)d_out;
    char* ws = (char*)d_ws;

    size_t colsz = (size_t)W64C * 128 * 8;                     // 3,276,800 B
    u64* colbits = (u64*)ws;
    u64* rowbits = (u64*)(ws + colsz);                         // 3,276,800 B
    u32* inter   = (u32*)(ws + 2 * colsz);                     // 65,536 B
    int* aidx    = (int*)(ws + 2 * colsz + 65536);

    float* out_anchor = out + (size_t)MBOX * SSAMP * 5;        // second output chunk

    kA<<<W64C / 4, 256, 0, stream>>>(points, boxes, colbits, rowbits, inter);
    kB<<<(MBOX / ITILE) * NCH, 256, 0, stream>>>(colbits, inter);
    kC<<<1, 256, 0, stream>>>(inter, labels, pNA, aidx, out_anchor);  // 256 threads!
    kD<<<MBOX, 256, 0, stream>>>(rowbits, aidx, points, out);
}

// Round 5
// 107.617 us; speedup vs baseline: 1.3132x; 1.3132x over previous
//
#pragma clang fp contract(off)
#include <hip/hip_runtime.h>
#include <hip/hip_bf16.h>

typedef unsigned long long u64;
typedef unsigned int u32;

#define NPTS   200000
#define MBOX   128
#define W64    3125      // NPTS / 64 exactly
#define W64C   3200      // padded word count (25 chunks * 128)
#define NCH    25
#define CW     128       // words per kB chunk
#define ITILE  8         // i-rows per kB block
#define SSAMP  256
#define AANCH  3
#define VOXELF 0.4f
#define PCSF   -75.2f

// ---------------- Kernel A: per-point 128-bit box masks -> col-major + row-major bitmaps ----
__global__ __launch_bounds__(256) void kA(const float* __restrict__ points,
                                          const float* __restrict__ boxes,
                                          u64* __restrict__ colbits,
                                          u64* __restrict__ rowbits,
                                          u32* __restrict__ inter)
{
    __shared__ float sbx[128], sby[128], sr[128], sqx[128], sqy[128], srv[128];
    int tid = threadIdx.x;
    // fold inter zero-init into this kernel (runs before kB in stream order)
    if (blockIdx.x < 64) inter[blockIdx.x * 256 + tid] = 0;
    if (tid < 128) {
        float bx = boxes[tid*7+0], by = boxes[tid*7+1];
        float dx = boxes[tid*7+3], dy = boxes[tid*7+4];
        float hx = dx * 0.5f, hy = dy * 0.5f;
        float sq = hx*hx;
        sq = sq + hy*hy;
        float r = sqrtf(sq);                     // radii (GAMMA=1)
        sbx[tid] = bx; sby[tid] = by; sr[tid] = r;
        sqx[tid] = floorf((bx - PCSF) / VOXELF);
        sqy[tid] = floorf((by - PCSF) / VOXELF);
        srv[tid] = ceilf(r / VOXELF);            // rad_vox
    }
    __syncthreads();
    int w = blockIdx.x * 4 + (tid >> 6);         // w in [0, W64C)
    int lane = tid & 63;
    int n = w * 64 + lane;
    bool valid = (n < NPTS);
    float px = 1e9f, py = 1e9f;
    if (valid) { px = points[n*5+0]; py = points[n*5+1]; }
    float cxn = floorf((px - PCSF) / VOXELF);
    float cyn = floorf((py - PCSF) / VOXELF);
    u64 lo = 0, hi = 0;
    bool voxany = false;
    for (int m = 0; m < 128; ++m) {
        float ddx = px - sbx[m], ddy = py - sby[m];
        float sq = ddx*ddx;
        sq = sq + ddy*ddy;
        float dis = sqrtf(sq);
        bool hit = (dis <= sr[m]);
        float aqx = fabsf(sqx[m] - cxn), aqy = fabsf(sqy[m] - cyn);
        bool vox = (aqx < srv[m]) & (aqy < srv[m]);
        voxany |= vox;
        if (m < 64) lo |= ((u64)hit) << m;
        else        hi |= ((u64)hit) << (m - 64);
    }
    if (!voxany) { lo = 0; hi = 0; }   // point_mask = circle & vmask
    u64 mylo = 0, myhi = 0;
    for (int m = 0; m < 64; ++m) {
        u64 bal = __ballot(((lo >> m) & 1ull) != 0);
        if (lane == m) mylo = bal;
    }
    for (int m = 0; m < 64; ++m) {
        u64 bal = __ballot(((hi >> m) & 1ull) != 0);
        if (lane == m) myhi = bal;
    }
    colbits[(size_t)w * 128 + lane]      = mylo;   // coalesced 512B per wave
    colbits[(size_t)w * 128 + 64 + lane] = myhi;
    rowbits[(size_t)lane * W64C + w]        = mylo; // scatter, 8B per lane
    rowbits[(size_t)(lane + 64) * W64C + w] = myhi;
}

// ---------------- Kernel B: inter[i][j] += popcount(row_i & row_j), tiled bit-GEMM ----------------
__global__ __launch_bounds__(256) void kB(const u64* __restrict__ colbits,
                                          u32* __restrict__ inter)
{
    __shared__ u64 ldsI[CW * ITILE];   // [k][i] : 8KB
    __shared__ u32 part[128 * ITILE];  // 4KB
    int blk = blockIdx.x;
    int itile = blk / NCH, ch = blk % NCH;
    int i0 = itile * ITILE, w0 = ch * CW;
    int tid = threadIdx.x;
    for (int idx = tid; idx < CW * ITILE; idx += 256) {
        int w = idx >> 3, i = idx & 7;
        ldsI[idx] = colbits[(size_t)(w0 + w) * 128 + i0 + i];
    }
    __syncthreads();
    int j = tid & 127, dup = tid >> 7;     // dup splits the w-chunk in half
    u32 acc[ITILE] = {0,0,0,0,0,0,0,0};
    int kbeg = dup * (CW/2), kend = kbeg + (CW/2);
    #pragma unroll 2
    for (int k = kbeg; k < kend; ++k) {
        u64 rj = colbits[(size_t)(w0 + k) * 128 + j];   // coalesced across lanes
        #pragma unroll
        for (int i = 0; i < ITILE; ++i)
            acc[i] += (u32)__popcll(rj & ldsI[k * ITILE + i]);
    }
    if (dup == 1) {
        #pragma unroll
        for (int i = 0; i < ITILE; ++i) part[j * ITILE + i] = acc[i];
    }
    __syncthreads();
    if (dup == 0) {
        #pragma unroll
        for (int i = 0; i < ITILE; ++i)
            atomicAdd(&inter[(i0 + i) * 128 + j], acc[i] + part[j * ITILE + i]);
    }
}

// ---------------- Kernel C1: fully-parallel miou argmax (one block per row i) --------------
__global__ __launch_bounds__(128) void kC1(const u32* __restrict__ inter,
                                           const int* __restrict__ labels,
                                           float* __restrict__ mmaxW,
                                           int* __restrict__ midxW)
{
    int i = blockIdx.x, j = threadIdx.x;
    u32 I  = inter[i * 128 + j];
    u32 ci = inter[i * 128 + i];          // broadcast
    u32 cj = inter[j * 128 + j];          // strided gather, L2-hit
    int li = labels[i], lj = labels[j];
    long un = (long)ci + (long)cj - (long)I;
    float v = 0.0f;
    if ((j != i) && (lj == li) && (un > 0))
        v = (float)I / fmaxf((float)un, 1.0f);
    // pack: larger value wins; ties -> smaller j (larger 127-j)
    u64 key = ((u64)__float_as_uint(v) << 32) | (u32)(127 - j);
    #pragma unroll
    for (int d = 1; d < 64; d <<= 1) {
        u64 o = __shfl_xor(key, d);
        key = (key > o) ? key : o;
    }
    __shared__ u64 wk[2];
    if ((j & 63) == 0) wk[j >> 6] = key;
    __syncthreads();
    if (j == 0) {
        u64 k = (wk[0] > wk[1]) ? wk[0] : wk[1];
        mmaxW[i] = __uint_as_float((u32)(k >> 32));
        midxW[i] = 127 - (int)(k & 0xffffffffu);
    }
}

// ---------------- Kernel C2: single-wave greedy grouping; state in VGPRs via shfl ----------
__global__ __launch_bounds__(64) void kC2(const float* __restrict__ mmaxW,
                                          const int* __restrict__ midxW,
                                          const int* __restrict__ pNA,
                                          int* __restrict__ aidx_ws,
                                          float* __restrict__ out_anchor)
{
    __shared__ int sA[128 * AANCH];
    int lane = threadIdx.x;
    int NA = *pNA;
    int   mia = midxW[lane], mib = midxW[lane + 64];
    float mxa = mmaxW[lane], mxb = mmaxW[lane + 64];
    int gofa = -1, gofb = -1;
    int gca = 0, gcb = 0;
    for (int t = lane; t < 128 * AANCH; t += 64) sA[t] = -1;
    int ng = 0;
    #pragma unroll 4
    for (int i = 0; i < 128; ++i) {
        int   j  = __shfl((i < 64) ? mia : mib, i & 63);   // static: hoistable
        float mx = __shfl((i < 64) ? mxa : mxb, i & 63);
        int   gj = __shfl((j < 64) ? gofa : gofb, j & 63); // chain: 1st bpermute
        int gjs = gj > 0 ? gj : 0;
        int   gc = __shfl((gjs < 64) ? gca : gcb, gjs & 63); // chain: 2nd bpermute
        bool join = (mx > 0.5f) && (gj >= 0) && (gc < NA);
        int tg = join ? gjs : ng;
        int ts = join ? gc : 0;
        if (lane == 0) sA[tg * AANCH + ts] = i;            // off-chain LDS write
        if (lane == (i & 63))  { if (i < 64)  gofa = tg; else gofb = tg; }
        if (lane == (tg & 63)) { if (tg < 64) gca += 1;  else gcb += 1; }
        ng += join ? 0 : 1;
    }
    __syncthreads();
    for (int t = lane; t < 128 * AANCH; t += 64) {
        int v = sA[t];
        aidx_ws[t] = v;
        out_anchor[t] = (float)v;      // int32 ref chunk read back as f32 values
    }
}

// ---------------- Kernel D: merged masks, ordered top-k selection, gather ----------------
__global__ __launch_bounds__(256) void kD(const u64* __restrict__ rowbits,
                                          const int* __restrict__ aidx_ws,
                                          const float* __restrict__ points,
                                          float* __restrict__ out)
{
    int g = blockIdx.x, tid = threadIdx.x;
    __shared__ u32 sl3[256], sl2[256], sl1[256];
    __shared__ u64 wtot[4];
    __shared__ u64 carried;
    float* outg = out + (size_t)g * SSAMP * 5;
    int a0 = aidx_ws[g*3+0], a1 = aidx_ws[g*3+1], a2 = aidx_ws[g*3+2];
    if (a0 < 0) {                      // invalid group -> all zeros
        for (int t = tid; t < SSAMP * 5; t += 256) outg[t] = 0.0f;
        return;
    }
    bool vB = (a1 >= 0), vC = (a2 >= 0);
    const u64* rA = rowbits + (size_t)a0 * W64C;
    const u64* rB = rowbits + (size_t)(vB ? a1 : 0) * W64C;
    const u64* rC = rowbits + (size_t)(vC ? a2 : 0) * W64C;
    if (tid == 0) carried = 0;
    __syncthreads();
    int lane = tid & 63, wv = tid >> 6;
    const u64 M21 = (1ull << 21) - 1;
    for (int ch = 0; ch < 13; ++ch) {
        int w = ch * 256 + tid;
        bool inr = (w < W64);
        u64 a = 0, b = 0, c = 0;
        if (inr) {
            a = rA[w];                          // coalesced
            b = vB ? rB[w] : 0ull;
            c = vC ? rC[w] : 0ull;
        }
        u64 m3 = a & b & c;
        u64 any2 = (a & b) | (a & c) | (b & c);
        u64 m2 = any2 & ~m3;
        u64 m1 = (a | b | c) & ~any2;
        u64 p = ((u64)__popcll(m3) << 42) | ((u64)__popcll(m2) << 21) | (u64)__popcll(m1);
        u64 own = p;
        for (int d = 1; d < 64; d <<= 1) {       // inclusive wave scan (packed fields)
            u64 t = __shfl_up(p, d);
            if (lane >= d) p += t;
        }
        if (lane == 63) wtot[wv] = p;
        u64 excl = p - own;
        __syncthreads();
        u64 off = carried + excl;
        for (int k = 0; k < wv; ++k) off += wtot[k];
        u32 e3 = (u32)(off >> 42);
        u32 e2 = (u32)((off >> 21) & M21);
        u32 e1 = (u32)(off & M21);
        int nb = w * 64;
        u64 mm = m3; u32 o = e3;
        while (mm) { int b2 = __builtin_ctzll(mm); mm &= mm - 1; if (o < 256) sl3[o] = nb + b2; o++; }
        mm = m2; o = e2;
        while (mm) { int b2 = __builtin_ctzll(mm); mm &= mm - 1; if (o < 256) sl2[o] = nb + b2; o++; }
        mm = m1; o = e1;
        while (mm) { int b2 = __builtin_ctzll(mm); mm &= mm - 1; if (o < 256) sl1[o] = nb + b2; o++; }
        __syncthreads();
        if (tid == 0) carried += wtot[0] + wtot[1] + wtot[2] + wtot[3];
        __syncthreads();
    }
    u64 car = carried;
    u32 t3 = (u32)(car >> 42), t2 = (u32)((car >> 21) & M21), t1 = (u32)(car & M21);
    u32 s = (u32)tid;
    int n = -1;
    if (s < t3)                 n = (int)sl3[s];
    else if (s < t3 + t2)       n = (int)sl2[s - t3];
    else if (s < t3 + t2 + t1)  n = (int)sl1[s - t3 - t2];
    float v0=0.f, v1=0.f, v2=0.f, v3=0.f, v4=0.f;
    if (n >= 0) {
        const float* pp = points + (size_t)n * 5;
        v0 = pp[0]; v1 = pp[1]; v2 = pp[2]; v3 = pp[3]; v4 = pp[4];
    }
    outg[s*5+0] = v0; outg[s*5+1] = v1; outg[s*5+2] = v2;
    outg[s*5+3] = v3; outg[s*5+4] = v4;
}

extern "C" void kernel_launch(void* const* d_in, const int* in_sizes, int n_in,
                              void* d_out, int out_size, void* d_ws, size_t ws_size,
                              hipStream_t stream)
{
    const float* points = (const float*)d_in[0];
    const float* boxes  = (const float*)d_in[1];
    const int*   labels = (const int*)d_in[2];
    const int*   pNA    = (const int*)d_in[4];
    float* out = (float*)d_out;
    char* ws = (char*)d_ws;

    size_t colsz = (size_t)W64C * 128 * 8;                     // 3,276,800 B
    u64* colbits = (u64*)ws;
    u64* rowbits = (u64*)(ws + colsz);                         // 3,276,800 B
    u32* inter   = (u32*)(ws + 2 * colsz);                     // 65,536 B
    int* aidx    = (int*)(ws + 2 * colsz + 65536);             // 1,536 B
    float* mmaxW = (float*)(ws + 2 * colsz + 65536 + 1536);    // 512 B
    int*   midxW = (int*)(ws + 2 * colsz + 65536 + 2048);      // 512 B

    float* out_anchor = out + (size_t)MBOX * SSAMP * 5;        // second output chunk

    kA<<<W64C / 4, 256, 0, stream>>>(points, boxes, colbits, rowbits, inter);
    kB<<<(MBOX / ITILE) * NCH, 256, 0, stream>>>(colbits, inter);
    kC1<<<MBOX, 128, 0, stream>>>(inter, labels, mmaxW, midxW);
    kC2<<<1, 64, 0, stream>>>(mmaxW, midxW, pNA, aidx, out_anchor);
    kD<<<MBOX, 256, 0, stream>>>(rowbits, aidx, points, out);
}

// Round 6
// 75.818 us; speedup vs baseline: 1.8639x; 1.4194x over previous
//
#pragma clang fp contract(off)
#include <hip/hip_runtime.h>
#include <hip/hip_bf16.h>

typedef unsigned long long u64;
typedef unsigned int u32;

#define NPTS   200000
#define MBOX   128
#define W64    3125      // NPTS / 64 exactly
#define W64C   3200      // padded row stride (u64 words)
#define SSAMP  256
#define AANCH  3
#define VOXELF 0.4f
#define PCSF   -75.2f
#define TILEW  9.375f    // 150/16
#define NTILE  16

// ---------------- Kernel Z: zero rowbits + inter (contiguous 3,342,336 B) ----------------
__global__ __launch_bounds__(256) void kZ(uint4* __restrict__ p)
{
    p[(size_t)blockIdx.x * 256 + threadIdx.x] = make_uint4(0, 0, 0, 0);
}

// ---------------- Kernel P: box params + per-tile candidate bitmasks ----------------
// bpk[m*8] = {bx,by,r,qx, qy,rv,0,0}; tmask[t*2+{0,1}] = 128-bit candidate set for tile t
__global__ __launch_bounds__(256) void kP(const float* __restrict__ boxes,
                                          float* __restrict__ bpk,
                                          u64* __restrict__ tmask)
{
    __shared__ float sbx[128], sby[128], srch[128];
    int tid = threadIdx.x;
    if (tid < 128) {
        float bx = boxes[tid*7+0], by = boxes[tid*7+1];
        float dx = boxes[tid*7+3], dy = boxes[tid*7+4];
        float hx = dx * 0.5f, hy = dy * 0.5f;
        float sq = hx*hx;
        sq = sq + hy*hy;
        float r = sqrtf(sq);                         // radii (GAMMA=1)
        float qx = floorf((bx - PCSF) / VOXELF);
        float qy = floorf((by - PCSF) / VOXELF);
        float rv = ceilf(r / VOXELF);                // rad_vox
        bpk[tid*8+0] = bx; bpk[tid*8+1] = by; bpk[tid*8+2] = r;  bpk[tid*8+3] = qx;
        bpk[tid*8+4] = qy; bpk[tid*8+5] = rv; bpk[tid*8+6] = 0.f; bpk[tid*8+7] = 0.f;
        sbx[tid] = bx; sby[tid] = by;
        srch[tid] = VOXELF * (rv + 2.0f);            // conservative reach (>=0.8m slack)
    }
    __syncthreads();
    int tx = tid & 15, ty = tid >> 4;
    float x0 = -75.0f + tx * TILEW, x1 = x0 + TILEW;
    float y0 = -75.0f + ty * TILEW, y1 = y0 + TILEW;
    u64 m0 = 0, m1 = 0;
    for (int m = 0; m < 128; ++m) {
        float rc = srch[m];
        bool c = (sbx[m] > x0 - rc) & (sbx[m] < x1 + rc) &
                 (sby[m] > y0 - rc) & (sby[m] < y1 + rc);
        if (m < 64) m0 |= ((u64)c) << m;
        else        m1 |= ((u64)c) << (m - 64);
    }
    tmask[tid*2]   = m0;
    tmask[tid*2+1] = m1;
}

// ---------------- Kernel A: tile-pruned masks -> sparse atomicOr rowbits + atomicAdd inter --
__global__ __launch_bounds__(256) void kA(const float* __restrict__ points,
                                          const float* __restrict__ bpk,
                                          const u64* __restrict__ tmask,
                                          u64* __restrict__ rowbits,
                                          u32* __restrict__ inter)
{
    __shared__ float4 sB4[128];     // {bx,by,r,qx}
    __shared__ float2 sB2[128];     // {qy,rv}
    __shared__ u64 sTM[512];
    int tid = threadIdx.x;
    if (tid < 128) {
        const float4* bp = (const float4*)bpk;
        float4 a = bp[tid*2];
        float4 b = bp[tid*2+1];
        sB4[tid] = a;
        sB2[tid] = make_float2(b.x, b.y);
    }
    sTM[tid]       = tmask[tid];
    sTM[tid + 256] = tmask[tid + 256];
    __syncthreads();

    int n = blockIdx.x * 256 + tid;
    if (n >= NPTS) return;
    float px = points[n*5+0], py = points[n*5+1];
    float cxn = floorf((px - PCSF) / VOXELF);
    float cyn = floorf((py - PCSF) / VOXELF);
    int tx = (int)floorf((px + 75.0f) * (1.0f / TILEW));
    int ty = (int)floorf((py + 75.0f) * (1.0f / TILEW));
    tx = tx < 0 ? 0 : (tx > 15 ? 15 : tx);
    ty = ty < 0 ? 0 : (ty > 15 ? 15 : ty);
    int tile = ty * 16 + tx;
    u64 c0 = sTM[tile*2], c1 = sTM[tile*2+1];
    u64 h0 = 0, h1 = 0;
    bool voxany = false;
    while (c0) {
        int m = __builtin_ctzll(c0); c0 &= c0 - 1;
        float4 bd = sB4[m]; float2 be = sB2[m];
        float ddx = px - bd.x, ddy = py - bd.y;
        float sq = ddx*ddx;
        sq = sq + ddy*ddy;
        float dis = sqrtf(sq);
        bool hit = (dis <= bd.z);
        bool vox = (fabsf(bd.w - cxn) < be.y) & (fabsf(be.x - cyn) < be.y);
        voxany |= vox;
        h0 |= ((u64)hit) << m;
    }
    while (c1) {
        int m = __builtin_ctzll(c1); c1 &= c1 - 1;
        float4 bd = sB4[m + 64]; float2 be = sB2[m + 64];
        float ddx = px - bd.x, ddy = py - bd.y;
        float sq = ddx*ddx;
        sq = sq + ddy*ddy;
        float dis = sqrtf(sq);
        bool hit = (dis <= bd.z);
        bool vox = (fabsf(bd.w - cxn) < be.y) & (fabsf(be.x - cyn) < be.y);
        voxany |= vox;
        h1 |= ((u64)hit) << m;
    }
    if (!voxany) { h0 = 0; h1 = 0; }       // point_mask = circle & vmask
    if ((h0 | h1) == 0) return;

    int w = n >> 6, lane = n & 63;
    u64 lanebit = 1ull << lane;
    u64 e = h0;
    while (e) {
        int m = __builtin_ctzll(e); e &= e - 1;
        atomicOr(&rowbits[(size_t)m * W64C + w], lanebit);
        u64 f = h0;
        while (f) { int j = __builtin_ctzll(f); f &= f - 1; atomicAdd(&inter[m*128 + j], 1u); }
        f = h1;
        while (f) { int j = __builtin_ctzll(f); f &= f - 1; atomicAdd(&inter[m*128 + 64 + j], 1u); }
    }
    e = h1;
    while (e) {
        int m = __builtin_ctzll(e); e &= e - 1;
        atomicOr(&rowbits[(size_t)(m + 64) * W64C + w], lanebit);
        u64 f = h0;
        while (f) { int j = __builtin_ctzll(f); f &= f - 1; atomicAdd(&inter[(m+64)*128 + j], 1u); }
        f = h1;
        while (f) { int j = __builtin_ctzll(f); f &= f - 1; atomicAdd(&inter[(m+64)*128 + 64 + j], 1u); }
    }
}

// ---------------- Kernel C1: fully-parallel miou argmax (one block per row i) --------------
__global__ __launch_bounds__(128) void kC1(const u32* __restrict__ inter,
                                           const int* __restrict__ labels,
                                           float* __restrict__ mmaxW,
                                           int* __restrict__ midxW)
{
    int i = blockIdx.x, j = threadIdx.x;
    u32 I  = inter[i * 128 + j];
    u32 ci = inter[i * 128 + i];          // broadcast
    u32 cj = inter[j * 128 + j];          // strided gather, L2-hit
    int li = labels[i], lj = labels[j];
    long un = (long)ci + (long)cj - (long)I;
    float v = 0.0f;
    if ((j != i) && (lj == li) && (un > 0))
        v = (float)I / fmaxf((float)un, 1.0f);
    // pack: larger value wins; ties -> smaller j (larger 127-j)
    u64 key = ((u64)__float_as_uint(v) << 32) | (u32)(127 - j);
    #pragma unroll
    for (int d = 1; d < 64; d <<= 1) {
        u64 o = __shfl_xor(key, d);
        key = (key > o) ? key : o;
    }
    __shared__ u64 wk[2];
    if ((j & 63) == 0) wk[j >> 6] = key;
    __syncthreads();
    if (j == 0) {
        u64 k = (wk[0] > wk[1]) ? wk[0] : wk[1];
        mmaxW[i] = __uint_as_float((u32)(k >> 32));
        midxW[i] = 127 - (int)(k & 0xffffffffu);
    }
}

// ---------------- Kernel C2: single-wave greedy grouping; state in VGPRs via shfl ----------
__global__ __launch_bounds__(64) void kC2(const float* __restrict__ mmaxW,
                                          const int* __restrict__ midxW,
                                          const int* __restrict__ pNA,
                                          int* __restrict__ aidx_ws,
                                          float* __restrict__ out_anchor)
{
    __shared__ int sA[128 * AANCH];
    int lane = threadIdx.x;
    int NA = *pNA;
    int   mia = midxW[lane], mib = midxW[lane + 64];
    float mxa = mmaxW[lane], mxb = mmaxW[lane + 64];
    int gofa = -1, gofb = -1;
    int gca = 0, gcb = 0;
    for (int t = lane; t < 128 * AANCH; t += 64) sA[t] = -1;
    int ng = 0;
    #pragma unroll 4
    for (int i = 0; i < 128; ++i) {
        int   j  = __shfl((i < 64) ? mia : mib, i & 63);   // static: hoistable
        float mx = __shfl((i < 64) ? mxa : mxb, i & 63);
        int   gj = __shfl((j < 64) ? gofa : gofb, j & 63); // chain: 1st bpermute
        int gjs = gj > 0 ? gj : 0;
        int   gc = __shfl((gjs < 64) ? gca : gcb, gjs & 63); // chain: 2nd bpermute
        bool join = (mx > 0.5f) && (gj >= 0) && (gc < NA);
        int tg = join ? gjs : ng;
        int ts = join ? gc : 0;
        if (lane == 0) sA[tg * AANCH + ts] = i;            // off-chain LDS write
        if (lane == (i & 63))  { if (i < 64)  gofa = tg; else gofb = tg; }
        if (lane == (tg & 63)) { if (tg < 64) gca += 1;  else gcb += 1; }
        ng += join ? 0 : 1;
    }
    __syncthreads();
    for (int t = lane; t < 128 * AANCH; t += 64) {
        int v = sA[t];
        aidx_ws[t] = v;
        out_anchor[t] = (float)v;      // int32 ref chunk read back as f32 values
    }
}

// ---------------- Kernel D: merged masks, ordered top-k selection, gather ----------------
__global__ __launch_bounds__(256) void kD(const u64* __restrict__ rowbits,
                                          const int* __restrict__ aidx_ws,
                                          const float* __restrict__ points,
                                          float* __restrict__ out)
{
    int g = blockIdx.x, tid = threadIdx.x;
    __shared__ u32 sl3[256], sl2[256], sl1[256];
    __shared__ u64 wtot[4];
    __shared__ u64 carried;
    float* outg = out + (size_t)g * SSAMP * 5;
    int a0 = aidx_ws[g*3+0], a1 = aidx_ws[g*3+1], a2 = aidx_ws[g*3+2];
    if (a0 < 0) {                      // invalid group -> all zeros
        for (int t = tid; t < SSAMP * 5; t += 256) outg[t] = 0.0f;
        return;
    }
    bool vB = (a1 >= 0), vC = (a2 >= 0);
    const u64* rA = rowbits + (size_t)a0 * W64C;
    const u64* rB = rowbits + (size_t)(vB ? a1 : 0) * W64C;
    const u64* rC = rowbits + (size_t)(vC ? a2 : 0) * W64C;
    if (tid == 0) carried = 0;
    __syncthreads();
    int lane = tid & 63, wv = tid >> 6;
    const u64 M21 = (1ull << 21) - 1;
    for (int ch = 0; ch < 13; ++ch) {
        int w = ch * 256 + tid;
        bool inr = (w < W64);
        u64 a = 0, b = 0, c = 0;
        if (inr) {
            a = rA[w];                          // coalesced
            b = vB ? rB[w] : 0ull;
            c = vC ? rC[w] : 0ull;
        }
        u64 m3 = a & b & c;
        u64 any2 = (a & b) | (a & c) | (b & c);
        u64 m2 = any2 & ~m3;
        u64 m1 = (a | b | c) & ~any2;
        u64 p = ((u64)__popcll(m3) << 42) | ((u64)__popcll(m2) << 21) | (u64)__popcll(m1);
        u64 own = p;
        for (int d = 1; d < 64; d <<= 1) {       // inclusive wave scan (packed fields)
            u64 t = __shfl_up(p, d);
            if (lane >= d) p += t;
        }
        if (lane == 63) wtot[wv] = p;
        u64 excl = p - own;
        __syncthreads();
        u64 off = carried + excl;
        for (int k = 0; k < wv; ++k) off += wtot[k];
        u32 e3 = (u32)(off >> 42);
        u32 e2 = (u32)((off >> 21) & M21);
        u32 e1 = (u32)(off & M21);
        int nb = w * 64;
        u64 mm = m3; u32 o = e3;
        while (mm) { int b2 = __builtin_ctzll(mm); mm &= mm - 1; if (o < 256) sl3[o] = nb + b2; o++; }
        mm = m2; o = e2;
        while (mm) { int b2 = __builtin_ctzll(mm); mm &= mm - 1; if (o < 256) sl2[o] = nb + b2; o++; }
        mm = m1; o = e1;
        while (mm) { int b2 = __builtin_ctzll(mm); mm &= mm - 1; if (o < 256) sl1[o] = nb + b2; o++; }
        __syncthreads();
        if (tid == 0) carried += wtot[0] + wtot[1] + wtot[2] + wtot[3];
        __syncthreads();
    }
    u64 car = carried;
    u32 t3 = (u32)(car >> 42), t2 = (u32)((car >> 21) & M21), t1 = (u32)(car & M21);
    u32 s = (u32)tid;
    int n = -1;
    if (s < t3)                 n = (int)sl3[s];
    else if (s < t3 + t2)       n = (int)sl2[s - t3];
    else if (s < t3 + t2 + t1)  n = (int)sl1[s - t3 - t2];
    float v0=0.f, v1=0.f, v2=0.f, v3=0.f, v4=0.f;
    if (n >= 0) {
        const float* pp = points + (size_t)n * 5;
        v0 = pp[0]; v1 = pp[1]; v2 = pp[2]; v3 = pp[3]; v4 = pp[4];
    }
    outg[s*5+0] = v0; outg[s*5+1] = v1; outg[s*5+2] = v2;
    outg[s*5+3] = v3; outg[s*5+4] = v4;
}

extern "C" void kernel_launch(void* const* d_in, const int* in_sizes, int n_in,
                              void* d_out, int out_size, void* d_ws, size_t ws_size,
                              hipStream_t stream)
{
    const float* points = (const float*)d_in[0];
    const float* boxes  = (const float*)d_in[1];
    const int*   labels = (const int*)d_in[2];
    const int*   pNA    = (const int*)d_in[4];
    float* out = (float*)d_out;
    char* ws = (char*)d_ws;

    size_t rowsz = (size_t)MBOX * W64C * 8;                    // 3,276,800 B
    u64* rowbits = (u64*)ws;
    u32* inter   = (u32*)(ws + rowsz);                         // 65,536 B (contiguous with rowbits for kZ)
    int* aidx    = (int*)(ws + rowsz + 65536);                 // 1,536 B
    float* mmaxW = (float*)(ws + rowsz + 65536 + 1536);        // 512 B
    int*   midxW = (int*)(ws + rowsz + 65536 + 2048);          // 512 B
    float* bpk   = (float*)(ws + rowsz + 65536 + 2560 + 1536); // 4,096 B (16B aligned)
    u64*   tmask = (u64*)(ws + rowsz + 65536 + 2560 + 1536 + 4096); // 4,096 B

    float* out_anchor = out + (size_t)MBOX * SSAMP * 5;        // second output chunk

    // zero rowbits+inter: 3,342,336 B = 816 blocks * 256 threads * 16 B
    kZ<<<816, 256, 0, stream>>>((uint4*)ws);
    kP<<<1, 256, 0, stream>>>(boxes, bpk, tmask);
    kA<<<(NPTS + 255) / 256, 256, 0, stream>>>(points, bpk, tmask, rowbits, inter);
    kC1<<<MBOX, 128, 0, stream>>>(inter, labels, mmaxW, midxW);
    kC2<<<1, 64, 0, stream>>>(mmaxW, midxW, pNA, aidx, out_anchor);
    kD<<<MBOX, 256, 0, stream>>>(rowbits, aidx, points, out);
}